// Round 3
// baseline (118.272 us; speedup 1.0000x reference)
//
#include <hip/hip_runtime.h>

typedef short bf16x8 __attribute__((ext_vector_type(8)));
typedef float f32x4 __attribute__((ext_vector_type(4)));
typedef float f32x16 __attribute__((ext_vector_type(16)));

#define KDIM 256
#define BT 128
#define BK 64

__device__ __forceinline__ unsigned short f2bf(float f) {
  unsigned u = __float_as_uint(f);
  unsigned r = (u + 0x7fffu + ((u >> 16) & 1u)) >> 16;  // RNE
  return (unsigned short)r;
}
__device__ __forceinline__ float bf2f(unsigned short b) {
  return __uint_as_float(((unsigned)b) << 16);
}

__device__ __forceinline__ void async_cp16(const void* g, void* l) {
  __builtin_amdgcn_global_load_lds(
      (const __attribute__((address_space(1))) unsigned int*)g,
      (__attribute__((address_space(3))) unsigned int*)l, 16, 0, 0);
}

// Kernel 1: fp32 -> bf16 convert, row sq (of bf16-rounded vals), column sums,
// sum(sq). 256 blocks x 32 rows. Also zeroes d_out (verified in r2).
__global__ __launch_bounds__(256) void mmd_stage(
    const float* __restrict__ src, const float* __restrict__ tgt, int ns,
    unsigned short* __restrict__ Tbf, float* __restrict__ sq,
    float* __restrict__ scol, float* __restrict__ sum_sq,
    float* __restrict__ out) {
  __shared__ float sp[256];
  __shared__ float rw[4];
  int t = threadIdx.x;
  if (blockIdx.x == 0 && t == 0) out[0] = 0.f;  // main runs after us (stream)
  int lane = t & 63, wave = t >> 6;
  sp[t] = 0.f;
  __syncthreads();
  int sub = t & 31;   // 8-elem group within row
  int rsel = t >> 5;  // row within 8-row group
  float colacc[8];
#pragma unroll
  for (int j = 0; j < 8; ++j) colacc[j] = 0.f;
  float tsq = 0.f;
#pragma unroll
  for (int it = 0; it < 4; ++it) {
    int r = blockIdx.x * 32 + it * 8 + rsel;
    const float* rp = (r < ns) ? (src + (size_t)r * KDIM)
                               : (tgt + (size_t)(r - ns) * KDIM);
    float4 v0 = *(const float4*)(rp + sub * 8);
    float4 v1 = *(const float4*)(rp + sub * 8 + 4);
    float vals[8] = {v0.x, v0.y, v0.z, v0.w, v1.x, v1.y, v1.z, v1.w};
    unsigned pk[4];
    float ssp = 0.f;
#pragma unroll
    for (int j = 0; j < 4; ++j) {
      unsigned short b0 = f2bf(vals[2 * j]);
      unsigned short b1 = f2bf(vals[2 * j + 1]);
      float x0 = bf2f(b0), x1 = bf2f(b1);
      pk[j] = (unsigned)b0 | ((unsigned)b1 << 16);
      ssp += x0 * x0 + x1 * x1;
      colacc[2 * j] += x0;
      colacc[2 * j + 1] += x1;
    }
    *(uint4*)(Tbf + (size_t)r * KDIM + sub * 8) =
        make_uint4(pk[0], pk[1], pk[2], pk[3]);
    tsq += ssp;
    float ss = ssp;
#pragma unroll
    for (int off = 16; off; off >>= 1) ss += __shfl_down(ss, off, 32);
    if (sub == 0) sq[r] = ss;
  }
#pragma unroll
  for (int j = 0; j < 8; ++j) atomicAdd(&sp[sub * 8 + j], colacc[j]);
#pragma unroll
  for (int off = 32; off; off >>= 1) tsq += __shfl_down(tsq, off, 64);
  if (lane == 0) rw[wave] = tsq;
  __syncthreads();
  atomicAdd(&scol[t], sp[t]);
  if (t == 0) atomicAdd(sum_sq, rw[0] + rw[1] + rw[2] + rw[3]);
}

__device__ __forceinline__ float2 pk_add(float2 a, float2 b) {
  return make_float2(a.x + b.x, a.y + b.y);
}
__device__ __forceinline__ float2 pk_mul(float2 a, float2 b) {
  return make_float2(a.x * b.x, a.y * b.y);
}
__device__ __forceinline__ float2 pk_fma(float2 a, float2 b, float2 c) {
  return make_float2(__builtin_fmaf(a.x, b.x, c.x),
                     __builtin_fmaf(a.y, b.y, c.y));
}

// Kernel 2: fused Gram-tile (MFMA) + L2 + 5-kernel sum + reduction.
// REVERT to the verified round-0 structure (128x128 tiles, 4 waves, 33 KiB
// LDS -> 4 blocks/CU, full-drain __syncthreads schedule: the 1-block/CU
// 256^2 deep pipeline measured 13.7% MfmaUtil — inter-block TLP beats
// lockstep pipelining at K=256).
// CHANGE vs round-0: 32x32x16 MFMA fragments instead of 16x16x32 —
// halves LDS-read bytes per FLOP (16 ds_read_b128 per 16 MFMA of 32.8kFLOP
// per wave-chunk, was 32 per 32 of 16.4kFLOP) and uses the slightly faster
// 32x32 pipe. Store-side swizzle identical (slot = octet ^ (row&7));
// read octet o = ks*2 + (lane>>5).
// Also fused: per-block coef (wave 0) replaces the prep2 launch (verified r2).
__global__ __launch_bounds__(256) void mmd_main(
    const unsigned short* __restrict__ Tbf, const float* __restrict__ sq,
    const float* __restrict__ scol, const float* __restrict__ sum_sq,
    float* __restrict__ out, int n, int halfTiles, float inv) {
  __shared__ short As[BT * BK];
  __shared__ short Bs[BT * BK];
  __shared__ float sqa[BT];
  __shared__ float sqb[BT];
  __shared__ float red[4];
  __shared__ float s_c4;

  int id = blockIdx.x;
  int bi = (int)((sqrtf(8.f * (float)id + 1.f) - 1.f) * 0.5f);
  while ((bi + 1) * (bi + 2) / 2 <= id) ++bi;
  while (bi * (bi + 1) / 2 > id) --bi;
  int bj = id - bi * (bi + 1) / 2;
  int rowBase = bi * BT, colBase = bj * BT;

  int t = threadIdx.x;
  int lane = t & 63, wave = t >> 6;

  // fused coef (wave 0): c4 = -log2e/(16*bw). s_c4 read only after the
  // K-loop's barriers, so no extra sync needed.
  if (wave == 0) {
    float4 v = *(const float4*)(scol + lane * 4);
    float p = v.x * v.x + v.y * v.y + v.z * v.z + v.w * v.w;
#pragma unroll
    for (int off = 32; off; off >>= 1) p += __shfl_down(p, off, 64);
    if (lane == 0) {
      double ssq = (double)p, S = (double)sum_sq[0], nn = (double)n;
      double bwv = (2.0 * nn * S - 2.0 * ssq) / (nn * nn - nn) / 4.0;
      s_c4 = (float)(-1.4426950408889634 / (bwv * 16.0));
    }
  }

  if (t < 128) sqa[t] = sq[rowBase + t];
  else sqb[t - 128] = sq[colBase + (t - 128)];

  f32x16 acc[2][2];
#pragma unroll
  for (int a = 0; a < 2; ++a)
#pragma unroll
    for (int b = 0; b < 2; ++b)
#pragma unroll
      for (int e = 0; e < 16; ++e) acc[a][b][e] = 0.f;

  int wrow = (wave >> 1) * 64, wcol = (wave & 1) * 64;
  // staging: lane -> (row=lane/8, swizzled octet = (lane%8) ^ (lane/8))
  int lrow = lane >> 3;
  int kgsw = (lane & 7) ^ lrow;
  // 32x32x16 fragment: row-in-frag = lane&31, k-half = lane>>5
  int frow = lane & 31;
  int khalf = lane >> 5;

  for (int c = 0; c < 4; ++c) {
    int k0 = c * BK;
#pragma unroll
    for (int j = 0; j < 4; ++j) {
      int R0 = j * 32 + wave * 8;
      int ldsoff = (j * 256 + wave * 64) * 8;  // shorts; HW adds lane*16B
      async_cp16(Tbf + (size_t)(rowBase + R0 + lrow) * KDIM + k0 + kgsw * 8,
                 &As[ldsoff]);
      async_cp16(Tbf + (size_t)(colBase + R0 + lrow) * KDIM + k0 + kgsw * 8,
                 &Bs[ldsoff]);
    }
    __syncthreads();
#pragma unroll
    for (int ks = 0; ks < 4; ++ks) {  // K-steps of 16 within the 64-chunk
      int o = ks * 2 + khalf;         // k-octet (8 bf16) index, 0..7
      bf16x8 af[2], bfv[2];
#pragma unroll
      for (int mt = 0; mt < 2; ++mt) {
        int r = wrow + mt * 32 + frow;
        int pg = o ^ (r & 7);  // undo XOR swizzle
        af[mt] = *(const bf16x8*)&As[r * BK + pg * 8];
      }
#pragma unroll
      for (int nt = 0; nt < 2; ++nt) {
        int r = wcol + nt * 32 + frow;
        int pg = o ^ (r & 7);
        bfv[nt] = *(const bf16x8*)&Bs[r * BK + pg * 8];
      }
#pragma unroll
      for (int mt = 0; mt < 2; ++mt)
#pragma unroll
        for (int nt = 0; nt < 2; ++nt)
          acc[mt][nt] = __builtin_amdgcn_mfma_f32_32x32x16_bf16(
              af[mt], bfv[nt], acc[mt][nt], 0, 0, 0);
    }
    __syncthreads();
  }

  // epilogue: 32x32 C/D layout col=lane&31, row=(reg&3)+8*(reg>>2)+4*(lane>>5)
  // [m74/m101]. e = exp2(c4*L2); kernel sum = e+e^2+e^4+e^8+e^16, f32x2-packed.
  float c4 = s_c4;
  float m2c4 = -2.f * c4;
  float2 m2v = make_float2(m2c4, m2c4);
  int rb = khalf * 4;  // +4*(lane>>5)
  float2 lsum2 = make_float2(0.f, 0.f);
#pragma unroll
  for (int mt = 0; mt < 2; ++mt) {
    f32x4 rq[4];
#pragma unroll
    for (int q = 0; q < 4; ++q)
      rq[q] = *(const f32x4*)&sqa[wrow + mt * 32 + 8 * q + rb];
#pragma unroll
    for (int nt = 0; nt < 2; ++nt) {
      float cb = sqb[wcol + nt * 32 + frow] * c4;
#pragma unroll
      for (int q = 0; q < 4; ++q) {
#pragma unroll
        for (int s = 0; s < 4; s += 2) {
          float2 g =
              make_float2(acc[mt][nt][q * 4 + s], acc[mt][nt][q * 4 + s + 1]);
          float2 sab = make_float2(rq[q][s] * c4 + cb, rq[q][s + 1] * c4 + cb);
          float2 u = pk_fma(g, m2v, sab);
          float2 e = make_float2(__builtin_amdgcn_exp2f(u.x),
                                 __builtin_amdgcn_exp2f(u.y));
          float2 e2 = pk_mul(e, e);
          float2 e4 = pk_mul(e2, e2);
          float2 e8 = pk_mul(e4, e4);
          float2 sm = pk_add(e, e2);
          sm = pk_add(sm, e4);
          sm = pk_add(sm, e8);
          sm = pk_fma(e8, e8, sm);  // + e^16
          lsum2 = pk_add(lsum2, sm);
        }
      }
    }
  }
  float lsum = lsum2.x + lsum2.y;
#pragma unroll
  for (int off = 32; off; off >>= 1) lsum += __shfl_down(lsum, off, 64);
  if (lane == 0) red[wave] = lsum;
  __syncthreads();
  if (t == 0) {
    float w = ((bi < halfTiles) == (bj < halfTiles)) ? 1.f : -1.f;
    float f = (bi == bj) ? 1.f : 2.f;
    atomicAdd(out, w * f * inv * (red[0] + red[1] + red[2] + red[3]));
  }
}

extern "C" void kernel_launch(void* const* d_in, const int* in_sizes, int n_in,
                              void* d_out, int out_size, void* d_ws,
                              size_t ws_size, hipStream_t stream) {
  const float* src = (const float*)d_in[0];
  const float* tgt = (const float*)d_in[1];
  int ns = in_sizes[0] / KDIM;   // 4096
  int ntr = in_sizes[1] / KDIM;  // 4096
  int n = ns + ntr;              // 8192

  char* ws = (char*)d_ws;
  unsigned short* Tbf = (unsigned short*)ws;  // 4 MiB bf16 matrix
  size_t off = (size_t)n * KDIM * sizeof(unsigned short);
  float* sq = (float*)(ws + off);     off += (size_t)n * 4;
  float* scol = (float*)(ws + off);   off += (size_t)KDIM * 4;
  float* sum_sq = (float*)(ws + off);

  // zero scol + sum_sq (ws is poisoned 0xAA before every call)
  hipMemsetAsync(scol, 0, (KDIM + 1) * sizeof(float), stream);

  mmd_stage<<<n / 32, 256, 0, stream>>>(src, tgt, ns, Tbf, sq, scol, sum_sq,
                                        (float*)d_out);

  int nb = n / BT;               // 64
  int nblk = nb * (nb + 1) / 2;  // 2080
  mmd_main<<<nblk, 256, 0, stream>>>(Tbf, sq, scol, sum_sq, (float*)d_out, n,
                                     ns / BT, 1.f / ((float)ns * (float)ns));
}

// Round 4
// 116.416 us; speedup vs baseline: 1.0159x; 1.0159x over previous
//
#include <hip/hip_runtime.h>

typedef short bf16x8 __attribute__((ext_vector_type(8)));
typedef float f32x4 __attribute__((ext_vector_type(4)));

#define KDIM 256
#define BT 128
#define BK 32
#define NC 8  // K chunks = 256/32

__device__ __forceinline__ unsigned short f2bf(float f) {
  unsigned u = __float_as_uint(f);
  unsigned r = (u + 0x7fffu + ((u >> 16) & 1u)) >> 16;  // RNE
  return (unsigned short)r;
}
__device__ __forceinline__ float bf2f(unsigned short b) {
  return __uint_as_float(((unsigned)b) << 16);
}

__device__ __forceinline__ void async_cp16(const void* g, void* l) {
  __builtin_amdgcn_global_load_lds(
      (const __attribute__((address_space(1))) unsigned int*)g,
      (__attribute__((address_space(3))) unsigned int*)l, 16, 0, 0);
}

// Kernel 1: fp32 -> bf16 convert, row sq (of bf16-rounded vals), column sums,
// sum(sq). 256 blocks x 32 rows. Also zeroes d_out. (verified r2/r3)
__global__ __launch_bounds__(256) void mmd_stage(
    const float* __restrict__ src, const float* __restrict__ tgt, int ns,
    unsigned short* __restrict__ Tbf, float* __restrict__ sq,
    float* __restrict__ scol, float* __restrict__ sum_sq,
    float* __restrict__ out) {
  __shared__ float sp[256];
  __shared__ float rw[4];
  int t = threadIdx.x;
  if (blockIdx.x == 0 && t == 0) out[0] = 0.f;  // main runs after us (stream)
  int lane = t & 63, wave = t >> 6;
  sp[t] = 0.f;
  __syncthreads();
  int sub = t & 31;   // 8-elem group within row
  int rsel = t >> 5;  // row within 8-row group
  float colacc[8];
#pragma unroll
  for (int j = 0; j < 8; ++j) colacc[j] = 0.f;
  float tsq = 0.f;
#pragma unroll
  for (int it = 0; it < 4; ++it) {
    int r = blockIdx.x * 32 + it * 8 + rsel;
    const float* rp = (r < ns) ? (src + (size_t)r * KDIM)
                               : (tgt + (size_t)(r - ns) * KDIM);
    float4 v0 = *(const float4*)(rp + sub * 8);
    float4 v1 = *(const float4*)(rp + sub * 8 + 4);
    float vals[8] = {v0.x, v0.y, v0.z, v0.w, v1.x, v1.y, v1.z, v1.w};
    unsigned pk[4];
    float ssp = 0.f;
#pragma unroll
    for (int j = 0; j < 4; ++j) {
      unsigned short b0 = f2bf(vals[2 * j]);
      unsigned short b1 = f2bf(vals[2 * j + 1]);
      float x0 = bf2f(b0), x1 = bf2f(b1);
      pk[j] = (unsigned)b0 | ((unsigned)b1 << 16);
      ssp += x0 * x0 + x1 * x1;
      colacc[2 * j] += x0;
      colacc[2 * j + 1] += x1;
    }
    *(uint4*)(Tbf + (size_t)r * KDIM + sub * 8) =
        make_uint4(pk[0], pk[1], pk[2], pk[3]);
    tsq += ssp;
    float ss = ssp;
#pragma unroll
    for (int off = 16; off; off >>= 1) ss += __shfl_down(ss, off, 32);
    if (sub == 0) sq[r] = ss;
  }
#pragma unroll
  for (int j = 0; j < 8; ++j) atomicAdd(&sp[sub * 8 + j], colacc[j]);
#pragma unroll
  for (int off = 32; off; off >>= 1) tsq += __shfl_down(tsq, off, 64);
  if (lane == 0) rw[wave] = tsq;
  __syncthreads();
  atomicAdd(&scol[t], sp[t]);
  if (t == 0) atomicAdd(sum_sq, rw[0] + rw[1] + rw[2] + rw[3]);
}

__device__ __forceinline__ float2 pk_add(float2 a, float2 b) {
  return make_float2(a.x + b.x, a.y + b.y);
}
__device__ __forceinline__ float2 pk_mul(float2 a, float2 b) {
  return make_float2(a.x * b.x, a.y * b.y);
}
__device__ __forceinline__ float2 pk_fma(float2 a, float2 b, float2 c) {
  return make_float2(__builtin_fmaf(a.x, b.x, c.x),
                     __builtin_fmaf(a.y, b.y, c.y));
}

#define BAR() __builtin_amdgcn_s_barrier()
#define LGKM0() asm volatile("s_waitcnt lgkmcnt(0)" ::: "memory")
#define VMC4() asm volatile("s_waitcnt vmcnt(4)" ::: "memory")
#define VMC0() asm volatile("s_waitcnt vmcnt(0)" ::: "memory")

// Kernel 2: fused Gram-tile (MFMA) + L2 + 5-kernel sum + reduction.
// 128x128 tiles (r0-verified structure), 16x16x32 frags (r3's 32x32 had
// 4 conflict-cyc/ds_read), BK=32 DOUBLE-BUFFERED (32 KiB LDS, 4 blocks/CU).
// Diagnosis r2/r3: MfmaUtil 13%, VALU 28%, HBM 4.6% -> latency/MLP-bound:
// per-chunk vmcnt(0) drain at the barrier exposed full L2 latency (convoy).
// Fix: counted-vmcnt prefetch (r1-verified pattern): at top of chunk c,
// stage(c+1) into buf^1 (WAR-safe: that buffer's readers finished at the
// PREVIOUS chunk's closing barrier), then vmcnt(4) drains exactly chunk c's
// 4 loads/wave, s_barrier publishes. Current data always arrives a full
// compute-phase early.
// Swizzle for 64B rows: store global octet g at slot (g+(row>>1))&3; read
// slot (kq+(r>>1))&3 -> per-16-lane phase covers all 8 bank-quads x2 (free).
// sqa/sqb LDS staging removed (epilogue reads L3-resident sq directly) so
// vmcnt bookkeeping stays exact. K-ascending accumulation order unchanged
// -> bit-identical result.
__global__ __launch_bounds__(256, 4) void mmd_main(
    const unsigned short* __restrict__ Tbf, const float* __restrict__ sq,
    const float* __restrict__ scol, const float* __restrict__ sum_sq,
    float* __restrict__ out, int n, int halfTiles, float inv) {
  __shared__ short As[2][BT * BK];  // 2 x 8 KiB
  __shared__ short Bs[2][BT * BK];
  __shared__ float red[4];
  __shared__ float s_c4;

  int id = blockIdx.x;
  int bi = (int)((sqrtf(8.f * (float)id + 1.f) - 1.f) * 0.5f);
  while ((bi + 1) * (bi + 2) / 2 <= id) ++bi;
  while (bi * (bi + 1) / 2 > id) --bi;
  int bj = id - bi * (bi + 1) / 2;
  int rowBase = bi * BT, colBase = bj * BT;

  int t = threadIdx.x;
  int lane = t & 63, wave = t >> 6;

  // fused coef (wave 0): c4 = -log2e/(16*bw). Loads consumed (shfl chain)
  // before stage(0) issues, so staging vmcnt counts stay exact.
  if (wave == 0) {
    float4 v = *(const float4*)(scol + lane * 4);
    float p = v.x * v.x + v.y * v.y + v.z * v.z + v.w * v.w;
#pragma unroll
    for (int off = 32; off; off >>= 1) p += __shfl_down(p, off, 64);
    if (lane == 0) {
      double ssq = (double)p, S = (double)sum_sq[0], nn = (double)n;
      double bwv = (2.0 * nn * S - 2.0 * ssq) / (nn * nn - nn) / 4.0;
      s_c4 = (float)(-1.4426950408889634 / (bwv * 16.0));
    }
    LGKM0();  // s_c4 ds_write committed before first BAR -> visible later
  }

  // staging: wave w, lane l, part i covers 16B line L = w*64 + i*256 + l:
  // row = L>>2 (0..127), slot = L&3, holds global octet g = (slot-(row>>1))&3
  int srow = wave * 16 + (lane >> 2);  // row for i=0; +64 for i=1
  int g0 = ((lane & 3) - (srow >> 1)) & 3;
  int g1 = ((lane & 3) - ((srow + 64) >> 1)) & 3;
  int ldsb0 = wave * 512;            // shorts; HW adds lane*16B
  int ldsb1 = wave * 512 + 2048;

  // fragment constants: frow = lane&15, kq = lane>>4 (octet 0..3 = full K=32)
  int wrow = (wave >> 1) * 64, wcol = (wave & 1) * 64;
  int frow = lane & 15;
  int kq = lane >> 4;

  auto stage = [&](int c) {
    int k0 = c * BK;
    short* Ad = As[c & 1];
    short* Bd = Bs[c & 1];
    async_cp16(Tbf + (size_t)(rowBase + srow) * KDIM + k0 + g0 * 8, Ad + ldsb0);
    async_cp16(Tbf + (size_t)(rowBase + srow + 64) * KDIM + k0 + g1 * 8,
               Ad + ldsb1);
    async_cp16(Tbf + (size_t)(colBase + srow) * KDIM + k0 + g0 * 8, Bd + ldsb0);
    async_cp16(Tbf + (size_t)(colBase + srow + 64) * KDIM + k0 + g1 * 8,
               Bd + ldsb1);
  };

  f32x4 acc[4][4];
#pragma unroll
  for (int a = 0; a < 4; ++a)
#pragma unroll
    for (int b = 0; b < 4; ++b) {
      f32x4 z = {0.f, 0.f, 0.f, 0.f};
      acc[a][b] = z;
    }

  stage(0);

#pragma unroll
  for (int c = 0; c < NC; ++c) {
    // prefetch next chunk into the other buffer (its readers finished at the
    // previous chunk's closing BAR), then drain exactly this chunk's loads.
    if (c < NC - 1) {
      stage(c + 1);
      VMC4();
    } else {
      VMC0();
    }
    BAR();  // chunk c's LDS globally visible

    const short* Ab = As[c & 1];
    const short* Bb = Bs[c & 1];
    bf16x8 af[4], bfv[4];
#pragma unroll
    for (int mt = 0; mt < 4; ++mt) {
      int r = wrow + mt * 16 + frow;
      int s = (kq + (r >> 1)) & 3;  // undo swizzle
      af[mt] = *(const bf16x8*)&Ab[r * BK + s * 8];
    }
#pragma unroll
    for (int nt = 0; nt < 4; ++nt) {
      int r = wcol + nt * 16 + frow;
      int s = (kq + (r >> 1)) & 3;
      bfv[nt] = *(const bf16x8*)&Bb[r * BK + s * 8];
    }
#pragma unroll
    for (int mt = 0; mt < 4; ++mt)
#pragma unroll
      for (int nt = 0; nt < 4; ++nt)
        acc[mt][nt] = __builtin_amdgcn_mfma_f32_16x16x32_bf16(
            af[mt], bfv[nt], acc[mt][nt], 0, 0, 0);
    BAR();  // all reads of buf[c&1] done before it is restaged next iter
  }

  // epilogue: C/D layout col=lane&15, row=(lane>>4)*4+reg [m89].
  // e = exp2(c4*L2); kernel sum = e+e^2+e^4+e^8+e^16, float2-packed.
  // sq read directly from global (32 KB, L3-resident across all blocks).
  float c4 = s_c4;
  float m2c4 = -2.f * c4;
  float2 m2v = make_float2(m2c4, m2c4);
  int ccol = lane & 15;
  int rb = (lane >> 4) * 4;
  float ra[16];
#pragma unroll
  for (int mt = 0; mt < 4; ++mt) {
    float4 rv = *(const float4*)(sq + rowBase + wrow + mt * 16 + rb);
    ra[mt * 4 + 0] = rv.x * c4;
    ra[mt * 4 + 1] = rv.y * c4;
    ra[mt * 4 + 2] = rv.z * c4;
    ra[mt * 4 + 3] = rv.w * c4;
  }
  float cbv[4];
#pragma unroll
  for (int nt = 0; nt < 4; ++nt)
    cbv[nt] = sq[colBase + wcol + nt * 16 + ccol] * c4;

  float2 lsum2 = make_float2(0.f, 0.f);
#pragma unroll
  for (int mt = 0; mt < 4; ++mt) {
#pragma unroll
    for (int nt = 0; nt < 4; ++nt) {
      float cb = cbv[nt];
#pragma unroll
      for (int rp = 0; rp < 4; rp += 2) {
        float2 g = make_float2(acc[mt][nt][rp], acc[mt][nt][rp + 1]);
        float2 sab =
            make_float2(ra[mt * 4 + rp] + cb, ra[mt * 4 + rp + 1] + cb);
        float2 u = pk_fma(g, m2v, sab);
        float2 e = make_float2(__builtin_amdgcn_exp2f(u.x),
                               __builtin_amdgcn_exp2f(u.y));
        float2 e2 = pk_mul(e, e);
        float2 e4 = pk_mul(e2, e2);
        float2 e8 = pk_mul(e4, e4);
        float2 sm = pk_add(e, e2);
        sm = pk_add(sm, e4);
        sm = pk_add(sm, e8);
        sm = pk_fma(e8, e8, sm);  // + e^16
        lsum2 = pk_add(lsum2, sm);
      }
    }
  }
  float lsum = lsum2.x + lsum2.y;
#pragma unroll
  for (int off = 32; off; off >>= 1) lsum += __shfl_down(lsum, off, 64);
  if (lane == 0) red[wave] = lsum;
  __syncthreads();
  if (t == 0) {
    float w = ((bi < halfTiles) == (bj < halfTiles)) ? 1.f : -1.f;
    float f = (bi == bj) ? 1.f : 2.f;
    atomicAdd(out, w * f * inv * (red[0] + red[1] + red[2] + red[3]));
  }
}

extern "C" void kernel_launch(void* const* d_in, const int* in_sizes, int n_in,
                              void* d_out, int out_size, void* d_ws,
                              size_t ws_size, hipStream_t stream) {
  const float* src = (const float*)d_in[0];
  const float* tgt = (const float*)d_in[1];
  int ns = in_sizes[0] / KDIM;   // 4096
  int ntr = in_sizes[1] / KDIM;  // 4096
  int n = ns + ntr;              // 8192

  char* ws = (char*)d_ws;
  unsigned short* Tbf = (unsigned short*)ws;  // 4 MiB bf16 matrix
  size_t off = (size_t)n * KDIM * sizeof(unsigned short);
  float* sq = (float*)(ws + off);     off += (size_t)n * 4;
  float* scol = (float*)(ws + off);   off += (size_t)KDIM * 4;
  float* sum_sq = (float*)(ws + off);

  // zero scol + sum_sq (ws is poisoned 0xAA before every call)
  hipMemsetAsync(scol, 0, (KDIM + 1) * sizeof(float), stream);

  mmd_stage<<<n / 32, 256, 0, stream>>>(src, tgt, ns, Tbf, sq, scol, sum_sq,
                                        (float*)d_out);

  int nb = n / BT;               // 64
  int nblk = nb * (nb + 1) / 2;  // 2080
  mmd_main<<<nblk, 256, 0, stream>>>(Tbf, sq, scol, sum_sq, (float*)d_out, n,
                                     ns / BT, 1.f / ((float)ns * (float)ns));
}

// Round 7
// 107.700 us; speedup vs baseline: 1.0982x; 1.0809x over previous
//
#include <hip/hip_runtime.h>

typedef short bf16x8 __attribute__((ext_vector_type(8)));
typedef float f32x4 __attribute__((ext_vector_type(4)));

#define KDIM 256
#define BT 128
#define BK 64

__device__ __forceinline__ unsigned short f2bf(float f) {
  unsigned u = __float_as_uint(f);
  unsigned r = (u + 0x7fffu + ((u >> 16) & 1u)) >> 16;  // RNE
  return (unsigned short)r;
}
__device__ __forceinline__ float bf2f(unsigned short b) {
  return __uint_as_float(((unsigned)b) << 16);
}

__device__ __forceinline__ void async_cp16(const void* g, void* l) {
  __builtin_amdgcn_global_load_lds(
      (const __attribute__((address_space(1))) unsigned int*)g,
      (__attribute__((address_space(3))) unsigned int*)l, 16, 0, 0);
}

// Kernel 1: fp32 -> bf16 convert, row sq (of bf16-rounded vals), column sums,
// sum(sq). 256 blocks x 32 rows. (r0-verified body.)
__global__ __launch_bounds__(256) void mmd_stage(
    const float* __restrict__ src, const float* __restrict__ tgt, int ns,
    unsigned short* __restrict__ Tbf, float* __restrict__ sq,
    float* __restrict__ scol, float* __restrict__ sum_sq) {
  __shared__ float sp[256];
  __shared__ float rw[4];
  int t = threadIdx.x;
  int lane = t & 63, wave = t >> 6;
  sp[t] = 0.f;
  __syncthreads();
  int sub = t & 31;   // 8-elem group within row
  int rsel = t >> 5;  // row within 8-row group
  float colacc[8];
#pragma unroll
  for (int j = 0; j < 8; ++j) colacc[j] = 0.f;
  float tsq = 0.f;
#pragma unroll
  for (int it = 0; it < 4; ++it) {
    int r = blockIdx.x * 32 + it * 8 + rsel;
    const float* rp = (r < ns) ? (src + (size_t)r * KDIM)
                               : (tgt + (size_t)(r - ns) * KDIM);
    float4 v0 = *(const float4*)(rp + sub * 8);
    float4 v1 = *(const float4*)(rp + sub * 8 + 4);
    float vals[8] = {v0.x, v0.y, v0.z, v0.w, v1.x, v1.y, v1.z, v1.w};
    unsigned pk[4];
    float ssp = 0.f;
#pragma unroll
    for (int j = 0; j < 4; ++j) {
      unsigned short b0 = f2bf(vals[2 * j]);
      unsigned short b1 = f2bf(vals[2 * j + 1]);
      float x0 = bf2f(b0), x1 = bf2f(b1);
      pk[j] = (unsigned)b0 | ((unsigned)b1 << 16);
      ssp += x0 * x0 + x1 * x1;
      colacc[2 * j] += x0;
      colacc[2 * j + 1] += x1;
    }
    *(uint4*)(Tbf + (size_t)r * KDIM + sub * 8) =
        make_uint4(pk[0], pk[1], pk[2], pk[3]);
    tsq += ssp;
    float ss = ssp;
#pragma unroll
    for (int off = 16; off; off >>= 1) ss += __shfl_down(ss, off, 32);
    if (sub == 0) sq[r] = ss;
  }
#pragma unroll
  for (int j = 0; j < 8; ++j) atomicAdd(&sp[sub * 8 + j], colacc[j]);
#pragma unroll
  for (int off = 32; off; off >>= 1) tsq += __shfl_down(tsq, off, 64);
  if (lane == 0) rw[wave] = tsq;
  __syncthreads();
  atomicAdd(&scol[t], sp[t]);
  if (t == 0) atomicAdd(sum_sq, rw[0] + rw[1] + rw[2] + rw[3]);
}

__device__ __forceinline__ float2 pk_add(float2 a, float2 b) {
  return make_float2(a.x + b.x, a.y + b.y);
}
__device__ __forceinline__ float2 pk_mul(float2 a, float2 b) {
  return make_float2(a.x * b.x, a.y * b.y);
}
__device__ __forceinline__ float2 pk_fma(float2 a, float2 b, float2 c) {
  return make_float2(__builtin_fmaf(a.x, b.x, c.x),
                     __builtin_fmaf(a.y, b.y, c.y));
}

// Kernel 2: fused Gram-tile (MFMA) + L2 + 5-kernel sum + reduction.
// Body = EXACT r0 structure (empirical best). Theory under test (r0/r3/r4
// all pinned at ~13% MfmaUtil regardless of schedule): 2080 same-address
// device atomicAdds serialize block retirement. This version: plain store
// of the weighted partial to partials[id] (kernel-boundary release makes it
// visible to the next kernel) — NO cross-block atomics/election. prep2
// stays fused (wave 0 computes s_c4; verified bit-identical r2-r4).
// (Identical to the r6 submission, which never ran: GPU acquisition timeout.)
__global__ __launch_bounds__(256) void mmd_main(
    const unsigned short* __restrict__ Tbf, const float* __restrict__ sq,
    const float* __restrict__ scol, const float* __restrict__ sum_sq,
    float* __restrict__ partials, int n, int halfTiles, float inv) {
  __shared__ short As[BT * BK];
  __shared__ short Bs[BT * BK];
  __shared__ float sqa[BT];
  __shared__ float sqb[BT];
  __shared__ float red[4];
  __shared__ float s_c4;

  int id = blockIdx.x;
  int bi = (int)((sqrtf(8.f * (float)id + 1.f) - 1.f) * 0.5f);
  while ((bi + 1) * (bi + 2) / 2 <= id) ++bi;
  while (bi * (bi + 1) / 2 > id) --bi;
  int bj = id - bi * (bi + 1) / 2;
  int rowBase = bi * BT, colBase = bj * BT;

  int t = threadIdx.x;
  int lane = t & 63, wave = t >> 6;

  // fused coef (wave 0): c4 = -log2e/(16*bw). s_c4 ds_write drains at the
  // first __syncthreads; read only after the K-loop's barriers.
  if (wave == 0) {
    float4 v = *(const float4*)(scol + lane * 4);
    float p = v.x * v.x + v.y * v.y + v.z * v.z + v.w * v.w;
#pragma unroll
    for (int off = 32; off; off >>= 1) p += __shfl_down(p, off, 64);
    if (lane == 0) {
      double ssq = (double)p, S = (double)sum_sq[0], nn = (double)n;
      double bwv = (2.0 * nn * S - 2.0 * ssq) / (nn * nn - nn) / 4.0;
      s_c4 = (float)(-1.4426950408889634 / (bwv * 16.0));
    }
  }

  if (t < 128) sqa[t] = sq[rowBase + t];
  else sqb[t - 128] = sq[colBase + (t - 128)];

  f32x4 acc[4][4];
#pragma unroll
  for (int a = 0; a < 4; ++a)
#pragma unroll
    for (int b = 0; b < 4; ++b) {
      f32x4 z = {0.f, 0.f, 0.f, 0.f};
      acc[a][b] = z;
    }

  int wrow = (wave >> 1) * 64, wcol = (wave & 1) * 64;
  // staging: lane -> (row=lane/8, swizzled kgroup = (lane%8) ^ (lane/8))
  int lrow = lane >> 3;
  int kgsw = (lane & 7) ^ lrow;
  // ds_read: fragment row = lane&15, k-quad = lane>>4
  int frow = lane & 15;
  int kq = lane >> 4;

  for (int c = 0; c < 4; ++c) {
    int k0 = c * BK;
#pragma unroll
    for (int j = 0; j < 4; ++j) {
      int R0 = j * 32 + wave * 8;
      int ldsoff = (j * 256 + wave * 64) * 8;  // shorts; HW adds lane*16B
      async_cp16(Tbf + (size_t)(rowBase + R0 + lrow) * KDIM + k0 + kgsw * 8,
                 &As[ldsoff]);
      async_cp16(Tbf + (size_t)(colBase + R0 + lrow) * KDIM + k0 + kgsw * 8,
                 &Bs[ldsoff]);
    }
    __syncthreads();
#pragma unroll
    for (int ks = 0; ks < 2; ++ks) {
      bf16x8 af[4], bfv[4];
#pragma unroll
      for (int mt = 0; mt < 4; ++mt) {
        int r = wrow + mt * 16 + frow;
        int pg = (ks * 4 + kq) ^ (r & 7);  // undo XOR swizzle
        af[mt] = *(const bf16x8*)&As[r * BK + pg * 8];
      }
#pragma unroll
      for (int nt = 0; nt < 4; ++nt) {
        int r = wcol + nt * 16 + frow;
        int pg = (ks * 4 + kq) ^ (r & 7);
        bfv[nt] = *(const bf16x8*)&Bs[r * BK + pg * 8];
      }
#pragma unroll
      for (int mt = 0; mt < 4; ++mt)
#pragma unroll
        for (int nt = 0; nt < 4; ++nt)
          acc[mt][nt] = __builtin_amdgcn_mfma_f32_16x16x32_bf16(
              af[mt], bfv[nt], acc[mt][nt], 0, 0, 0);
    }
    __syncthreads();
  }

  // epilogue: C/D layout col=lane&15, row=(lane>>4)*4+reg  [m89]
  float c4 = s_c4;
  float m2c4 = -2.f * c4;
  float2 m2v = make_float2(m2c4, m2c4);
  int ccol = lane & 15;
  int rb = (lane >> 4) * 4;
  float ra[16];
#pragma unroll
  for (int mt = 0; mt < 4; ++mt)
#pragma unroll
    for (int rg = 0; rg < 4; ++rg)
      ra[mt * 4 + rg] = sqa[wrow + mt * 16 + rb + rg] * c4;
  float cbv[4];
#pragma unroll
  for (int nt = 0; nt < 4; ++nt) cbv[nt] = sqb[wcol + nt * 16 + ccol] * c4;

  float2 lsum2 = make_float2(0.f, 0.f);
#pragma unroll
  for (int mt = 0; mt < 4; ++mt) {
#pragma unroll
    for (int nt = 0; nt < 4; ++nt) {
      float cb = cbv[nt];
#pragma unroll
      for (int rp = 0; rp < 4; rp += 2) {
        float2 g = make_float2(acc[mt][nt][rp], acc[mt][nt][rp + 1]);
        float2 sab = make_float2(ra[mt * 4 + rp] + cb, ra[mt * 4 + rp + 1] + cb);
        float2 u = pk_fma(g, m2v, sab);
        float2 e = make_float2(__builtin_amdgcn_exp2f(u.x),
                               __builtin_amdgcn_exp2f(u.y));
        float2 e2 = pk_mul(e, e);
        float2 e4 = pk_mul(e2, e2);
        float2 e8 = pk_mul(e4, e4);
        float2 s = pk_add(e, e2);
        s = pk_add(s, e4);
        s = pk_add(s, e8);
        s = pk_fma(e8, e8, s);  // + e^16
        lsum2 = pk_add(lsum2, s);
      }
    }
  }
  float lsum = lsum2.x + lsum2.y;
#pragma unroll
  for (int off = 32; off; off >>= 1) lsum += __shfl_down(lsum, off, 64);
  if (lane == 0) red[wave] = lsum;
  __syncthreads();
  if (t == 0) {
    float w = ((bi < halfTiles) == (bj < halfTiles)) ? 1.f : -1.f;
    float f = (bi == bj) ? 1.f : 2.f;
    partials[id] = w * f * inv * (red[0] + red[1] + red[2] + red[3]);
  }
}

// Kernel 3: reduce 2080 partials -> out[0]. One block, ~2 us.
__global__ __launch_bounds__(256) void mmd_reduce(
    const float* __restrict__ partials, int nblk, float* __restrict__ out) {
  __shared__ float red[4];
  int t = threadIdx.x;
  int lane = t & 63, wave = t >> 6;
  float a = 0.f;
  for (int j = t; j < nblk; j += 256) a += partials[j];
#pragma unroll
  for (int off = 32; off; off >>= 1) a += __shfl_down(a, off, 64);
  if (lane == 0) red[wave] = a;
  __syncthreads();
  if (t == 0) out[0] = red[0] + red[1] + red[2] + red[3];
}

extern "C" void kernel_launch(void* const* d_in, const int* in_sizes, int n_in,
                              void* d_out, int out_size, void* d_ws,
                              size_t ws_size, hipStream_t stream) {
  const float* src = (const float*)d_in[0];
  const float* tgt = (const float*)d_in[1];
  int ns = in_sizes[0] / KDIM;   // 4096
  int ntr = in_sizes[1] / KDIM;  // 4096
  int n = ns + ntr;              // 8192

  char* ws = (char*)d_ws;
  unsigned short* Tbf = (unsigned short*)ws;  // 4 MiB bf16 matrix
  size_t off = (size_t)n * KDIM * sizeof(unsigned short);
  float* sq = (float*)(ws + off);       off += (size_t)n * 4;
  float* scol = (float*)(ws + off);     off += (size_t)KDIM * 4;
  float* sum_sq = (float*)(ws + off);   off += 4;
  float* partials = (float*)(ws + off);

  // zero scol + sum_sq (ws is poisoned 0xAA before every call)
  hipMemsetAsync(scol, 0, (KDIM + 1) * sizeof(float), stream);

  mmd_stage<<<n / 32, 256, 0, stream>>>(src, tgt, ns, Tbf, sq, scol, sum_sq);

  int nb = n / BT;               // 64
  int nblk = nb * (nb + 1) / 2;  // 2080
  mmd_main<<<nblk, 256, 0, stream>>>(Tbf, sq, scol, sum_sq, partials, n,
                                     ns / BT, 1.f / ((float)ns * (float)ns));
  mmd_reduce<<<1, 256, 0, stream>>>(partials, nblk, (float*)d_out);
}